// Round 13
// baseline (607.534 us; speedup 1.0000x reference)
//
#include <hip/hip_runtime.h>
#include <stdint.h>

typedef float  f32x4  __attribute__((ext_vector_type(4)));
typedef short  short8 __attribute__((ext_vector_type(8)));
typedef __bf16 bf16x8 __attribute__((ext_vector_type(8)));

__device__ __forceinline__ unsigned short f2bf(float f) {
    unsigned u = __builtin_bit_cast(unsigned, f);
    unsigned r = u + 0x7fffu + ((u >> 16) & 1u);   // round-to-nearest-even
    return (unsigned short)(r >> 16);
}

__device__ __forceinline__ short8 cvt8(f32x4 a, f32x4 b) {
    short8 r;
    r[0] = (short)f2bf(a[0]); r[1] = (short)f2bf(a[1]);
    r[2] = (short)f2bf(a[2]); r[3] = (short)f2bf(a[3]);
    r[4] = (short)f2bf(b[0]); r[5] = (short)f2bf(b[1]);
    r[6] = (short)f2bf(b[2]); r[7] = (short)f2bf(b[3]);
    return r;
}

typedef const __attribute__((address_space(1))) void* gas_p;
typedef __attribute__((address_space(3))) void*       las_p;
__device__ __forceinline__ void gld_lds16(const void* g, void* l) {
    __builtin_amdgcn_global_load_lds((gas_p)g, (las_p)l, 16, 0, 0);
}

__device__ __forceinline__ f32x4 mfma16(short8 a, short8 b, f32x4 c) {
    return __builtin_amdgcn_mfma_f32_16x16x32_bf16(
        __builtin_bit_cast(bf16x8, a), __builtin_bit_cast(bf16x8, b), c, 0, 0, 0);
}

// ---------------------------------------------------------------------------
// Small GEMM:  St[n][m] = sum_k X[m][k] * W[k][n]   (K = 128 fixed)
// (unchanged — validated, ~2% of runtime)
// ---------------------------------------------------------------------------
template<int NMAT>
__global__ __launch_bounds__(256) void k_xw_t(const float* __restrict__ X,
                                              const float* __restrict__ W,
                                              short* __restrict__ St, int M) {
    constexpr int K   = 128;
    constexpr int NPT = NMAT / 4;
    __shared__ float Xs[64][129];
    __shared__ float Ws[K][NMAT];

    const int tid = threadIdx.x;
    const int m0  = blockIdx.x * 64;

    constexpr int WCH = K * NMAT / 4 / 256;
    #pragma unroll
    for (int j = 0; j < WCH; ++j) {
        int ch = tid + j * 256;
        ((float4*)Ws)[ch] = ((const float4*)W)[ch];
    }
    #pragma unroll
    for (int j = 0; j < 8; ++j) {
        int ch = tid + j * 256;
        int r = ch >> 5, c4 = ch & 31;
        float4 v = *(const float4*)(X + (size_t)(m0 + r) * K + c4 * 4);
        Xs[r][c4 * 4 + 0] = v.x; Xs[r][c4 * 4 + 1] = v.y;
        Xs[r][c4 * 4 + 2] = v.z; Xs[r][c4 * 4 + 3] = v.w;
    }
    __syncthreads();

    const int m  = tid & 63;
    const int n0 = (tid >> 6) * NPT;
    float acc[NPT];
    #pragma unroll
    for (int i = 0; i < NPT; ++i) acc[i] = 0.f;

    for (int k = 0; k < K; ++k) {
        float x = Xs[m][k];
        #pragma unroll
        for (int i = 0; i < NPT; i += 4) {
            float4 w = *(const float4*)&Ws[k][n0 + i];
            acc[i + 0] += x * w.x; acc[i + 1] += x * w.y;
            acc[i + 2] += x * w.z; acc[i + 3] += x * w.w;
        }
    }
    #pragma unroll
    for (int i = 0; i < NPT; ++i)
        St[(size_t)(n0 + i) * M + m0 + m] = (short)f2bf(acc[i]);
}

// ---------------------------------------------------------------------------
// GEMM 1:  h = relu(adj @ S1 + b1), and SIDE-WRITE adj as blocked bf16:
//   adj16 chunk (b, kt) = 8 KB contiguous; thread tid owns [tid*32, tid*32+32)
//   = its fa0||fa1 (bit-exact the frags this kernel feeds MFMA).
//  Structure = r11 (BM=64, 4 waves x 16 excl rows, batch-4 A prefetch,
//  quad-buffered B DMA, one barrier/iter). Stores pinned after MFMA.
//  vmcnt (re-derived with 2 stores/iter in stream): VMH=BCH+18, VML=BCH+2.
// ---------------------------------------------------------------------------
__global__ __launch_bounds__(256, 1) void k_adj_cvt(const float* __restrict__ A,
                                                    const short* __restrict__ Bt,
                                                    const float* __restrict__ bias,
                                                    float* __restrict__ out,
                                                    char* __restrict__ adj16,
                                                    int M, int K) {
    constexpr int BM  = 64, BK = 64, BN = 128;
    constexpr int NF  = BN / 16;                     // 8
    constexpr int BCH = BN * BK * 2 / (256 * 16);    // 4
    constexpr int VMH = BCH + 18;                    // 22 (p0, p3)
    constexpr int VML = BCH + 2;                     // 6  (p1, p2)

    __shared__ short Bs[4][BN * 64];                 // 4 x 16 KB

    const int tid  = threadIdx.x;
    const int wave = tid >> 6, lane = tid & 63;
    const int lr   = lane & 15, lk = lane >> 4;
    const int row0 = blockIdx.x * BM;
    const int row_g = row0 + wave * 16 + lr;

    const char* Abase = (const char*)A + (size_t)row_g * K * 4 + lk * 32;
    char* Cbase = adj16 + (size_t)blockIdx.x * 256 * 8192 + tid * 32;

    const int key   = (lr & 7) << 4;
    const int offs0 = (lk * 16) ^ key;
    const int offs1 = (64 + lk * 16) ^ key;

    f32x4 acc[NF];
    #pragma unroll
    for (int n = 0; n < NF; ++n) acc[n] = (f32x4)0.f;

    f32x4 bA0[16], bA1[16];
    const int NT  = K / BK;                          // 256
    const int NTM = NT - 1;

#define LOAD_SLOT(QARR, BI, TT)                                                 \
    {                                                                           \
        const char* p = Abase + (size_t)(TT) * 256;                             \
        QARR[(BI) + 0] = *(const f32x4*)(p);                                    \
        QARR[(BI) + 1] = *(const f32x4*)(p + 16);                               \
        QARR[(BI) + 2] = *(const f32x4*)(p + 128);                              \
        QARR[(BI) + 3] = *(const f32x4*)(p + 144);                              \
    }
#define LOAD_BATCH(QARR, T0)                                                    \
    {                                                                           \
        LOAD_SLOT(QARR, 0,  ((T0) + 0) & NTM)                                   \
        LOAD_SLOT(QARR, 4,  ((T0) + 1) & NTM)                                   \
        LOAD_SLOT(QARR, 8,  ((T0) + 2) & NTM)                                   \
        LOAD_SLOT(QARR, 12, ((T0) + 3) & NTM)                                   \
    }
#define STAGE_B(BUF, KTP)                                                       \
    {                                                                           \
        _Pragma("unroll")                                                       \
        for (int j = 0; j < BCH; ++j) {                                         \
            int o = (tid + j * 256) * 16;                                       \
            int r = o >> 7, w = o & 127;                                        \
            const char* src = (const char*)Bt + (size_t)r * (K * 2)             \
                              + (size_t)((KTP) & NTM) * 128 + (w ^ ((r & 7) << 4)); \
            gld_lds16(src, (char*)&Bs[BUF][0] + o);                             \
        }                                                                       \
    }

    LOAD_BATCH(bA0, 0)
    STAGE_B(0, 0)
    LOAD_BATCH(bA1, 4)

#define ITER(KT, QARR, J4, CB, NB, VM, BATCH_STMT)                              \
    {                                                                           \
        short8 fa0 = cvt8(QARR[(J4) + 0], QARR[(J4) + 1]);                      \
        short8 fa1 = cvt8(QARR[(J4) + 2], QARR[(J4) + 3]);                      \
        { int ktn = ((KT) + 1) & NTM; STAGE_B(NB, ktn) }                        \
        BATCH_STMT                                                              \
        __builtin_amdgcn_sched_barrier(0);                                      \
        asm volatile("s_waitcnt vmcnt(%0)" :: "i"(VM) : "memory");              \
        __builtin_amdgcn_s_barrier();                                           \
        __builtin_amdgcn_sched_barrier(0);                                      \
        _Pragma("unroll")                                                       \
        for (int n = 0; n < NF; ++n) {                                          \
            short8 b0 = *(const short8*)((const char*)&Bs[CB][0]                \
                                         + n * 2048 + lr * 128 + offs0);        \
            acc[n] = mfma16(fa0, b0, acc[n]);                                   \
            short8 b1 = *(const short8*)((const char*)&Bs[CB][0]                \
                                         + n * 2048 + lr * 128 + offs1);        \
            acc[n] = mfma16(fa1, b1, acc[n]);                                   \
        }                                                                       \
        __builtin_amdgcn_sched_barrier(0);                                      \
        { char* dst = Cbase + (size_t)(KT) * 8192;                              \
          *(short8*)(dst) = fa0; *(short8*)(dst + 16) = fa1; }                  \
    }

    for (int g = 0; g < 32; ++g) {
        int t = g * 8;
        ITER(t + 0, bA0, 0,  0, 1, VMH, )
        ITER(t + 1, bA0, 4,  1, 2, VML, )
        ITER(t + 2, bA0, 8,  2, 3, VML, )
        ITER(t + 3, bA0, 12, 3, 0, VMH, LOAD_BATCH(bA0, (t + 3) + 5))
        ITER(t + 4, bA1, 0,  0, 1, VMH, )
        ITER(t + 5, bA1, 4,  1, 2, VML, )
        ITER(t + 6, bA1, 8,  2, 3, VML, )
        ITER(t + 7, bA1, 12, 3, 0, VMH, LOAD_BATCH(bA1, (t + 7) + 5))
    }
#undef ITER
#undef STAGE_B
#undef LOAD_BATCH
#undef LOAD_SLOT

    #pragma unroll
    for (int n = 0; n < NF; ++n) {
        int col = n * 16 + lr;
        float bv = bias[col];
        #pragma unroll
        for (int j = 0; j < 4; ++j) {
            int row = row0 + wave * 16 + lk * 4 + j;
            out[(size_t)row * BN + col] = fmaxf(acc[n][j] + bv, 0.f);
        }
    }
}

// ---------------------------------------------------------------------------
// GEMM 2:  out = adj @ S2 + b2, A read from blocked bf16 (chunk(b,kt)=8 KB,
//  thread tid reads [tid*32, +32) = its fa0||fa1 directly — FULLY contiguous
//  A stream, no cvt). Same r11 schedule; batch = 8 loads; VMH=10, VML=2.
// ---------------------------------------------------------------------------
__global__ __launch_bounds__(256, 1) void k_adj_pre(const char* __restrict__ adj16,
                                                    const short* __restrict__ Bt,
                                                    const float* __restrict__ bias,
                                                    float* __restrict__ out,
                                                    int M, int K) {
    constexpr int BM  = 64, BK = 64, BN = 64;
    constexpr int NF  = BN / 16;                     // 4
    constexpr int BCH = BN * BK * 2 / (256 * 16);    // 2
    constexpr int VMH = BCH + 8;                     // 10 (p0, p3)
    constexpr int VML = BCH;                         // 2  (p1, p2)

    __shared__ short Bs[4][BN * 64];                 // 4 x 8 KB

    const int tid  = threadIdx.x;
    const int wave = tid >> 6, lane = tid & 63;
    const int lr   = lane & 15, lk = lane >> 4;
    const int row0 = blockIdx.x * BM;

    const char* Cbase = adj16 + (size_t)blockIdx.x * 256 * 8192 + tid * 32;

    const int key   = (lr & 7) << 4;
    const int offs0 = (lk * 16) ^ key;
    const int offs1 = (64 + lk * 16) ^ key;

    f32x4 acc[NF];
    #pragma unroll
    for (int n = 0; n < NF; ++n) acc[n] = (f32x4)0.f;

    uint4 bA0[8], bA1[8];                            // 2 per tile x 4 tiles
    const int NT  = K / BK;                          // 256
    const int NTM = NT - 1;

#define LOAD_SLOT(QARR, BI, TT)                                                 \
    {                                                                           \
        const char* p = Cbase + (size_t)(TT) * 8192;                            \
        QARR[(BI) + 0] = *(const uint4*)(p);                                    \
        QARR[(BI) + 1] = *(const uint4*)(p + 16);                               \
    }
#define LOAD_BATCH(QARR, T0)                                                    \
    {                                                                           \
        LOAD_SLOT(QARR, 0, ((T0) + 0) & NTM)                                    \
        LOAD_SLOT(QARR, 2, ((T0) + 1) & NTM)                                    \
        LOAD_SLOT(QARR, 4, ((T0) + 2) & NTM)                                    \
        LOAD_SLOT(QARR, 6, ((T0) + 3) & NTM)                                    \
    }
#define STAGE_B(BUF, KTP)                                                       \
    {                                                                           \
        _Pragma("unroll")                                                       \
        for (int j = 0; j < BCH; ++j) {                                         \
            int o = (tid + j * 256) * 16;                                       \
            int r = o >> 7, w = o & 127;                                        \
            const char* src = (const char*)Bt + (size_t)r * (K * 2)             \
                              + (size_t)((KTP) & NTM) * 128 + (w ^ ((r & 7) << 4)); \
            gld_lds16(src, (char*)&Bs[BUF][0] + o);                             \
        }                                                                       \
    }

    LOAD_BATCH(bA0, 0)
    STAGE_B(0, 0)
    LOAD_BATCH(bA1, 4)

#define ITER(KT, QARR, J4, CB, NB, VM, BATCH_STMT)                              \
    {                                                                           \
        short8 fa0 = __builtin_bit_cast(short8, QARR[(J4) + 0]);                \
        short8 fa1 = __builtin_bit_cast(short8, QARR[(J4) + 1]);                \
        { int ktn = ((KT) + 1) & NTM; STAGE_B(NB, ktn) }                        \
        BATCH_STMT                                                              \
        __builtin_amdgcn_sched_barrier(0);                                      \
        asm volatile("s_waitcnt vmcnt(%0)" :: "i"(VM) : "memory");              \
        __builtin_amdgcn_s_barrier();                                           \
        __builtin_amdgcn_sched_barrier(0);                                      \
        _Pragma("unroll")                                                       \
        for (int n = 0; n < NF; ++n) {                                          \
            short8 b0 = *(const short8*)((const char*)&Bs[CB][0]                \
                                         + n * 2048 + lr * 128 + offs0);        \
            acc[n] = mfma16(fa0, b0, acc[n]);                                   \
            short8 b1 = *(const short8*)((const char*)&Bs[CB][0]                \
                                         + n * 2048 + lr * 128 + offs1);        \
            acc[n] = mfma16(fa1, b1, acc[n]);                                   \
        }                                                                       \
    }

    for (int g = 0; g < 32; ++g) {
        int t = g * 8;
        ITER(t + 0, bA0, 0, 0, 1, VMH, )
        ITER(t + 1, bA0, 2, 1, 2, VML, )
        ITER(t + 2, bA0, 4, 2, 3, VML, )
        ITER(t + 3, bA0, 6, 3, 0, VMH, LOAD_BATCH(bA0, (t + 3) + 5))
        ITER(t + 4, bA1, 0, 0, 1, VMH, )
        ITER(t + 5, bA1, 2, 1, 2, VML, )
        ITER(t + 6, bA1, 4, 2, 3, VML, )
        ITER(t + 7, bA1, 6, 3, 0, VMH, LOAD_BATCH(bA1, (t + 7) + 5))
    }
#undef ITER
#undef STAGE_B
#undef LOAD_BATCH
#undef LOAD_SLOT

    #pragma unroll
    for (int n = 0; n < NF; ++n) {
        int col = n * 16 + lr;
        float bv = bias[col];
        #pragma unroll
        for (int j = 0; j < 4; ++j) {
            int row = row0 + wave * 16 + lk * 4 + j;
            out[(size_t)row * BN + col] = acc[n][j] + bv;
        }
    }
}

extern "C" void kernel_launch(void* const* d_in, const int* in_sizes, int n_in,
                              void* d_out, int out_size, void* d_ws, size_t ws_size,
                              hipStream_t stream) {
    const int N = 16384, NH1 = 128, NH2 = 64;
    const float* feature = (const float*)d_in[0];
    const float* adj     = (const float*)d_in[1];
    const float* W1      = (const float*)d_in[2];
    const float* b1      = (const float*)d_in[3];
    const float* W2      = (const float*)d_in[4];
    const float* b2      = (const float*)d_in[5];

    // workspace: 16 MiB of small buffers + 512 MiB blocked-bf16 adj copy
    // (harness ws poison fill is 4.3 GB -> ws_size ~4 GiB, fits)
    short* S1t  = (short*)d_ws;                           // [128][16384] bf16, 4 MiB
    float* h    = (float*)((char*)d_ws + (4u << 20));     // [16384][128] fp32, 8 MiB
    short* S2t  = (short*)((char*)d_ws + (12u << 20));    // [64][16384]  bf16, 2 MiB
    char*  a16  = (char*)d_ws + (16u << 20);              // blocked bf16 adj, 512 MiB

    k_xw_t<NH1><<<N / 64, 256, 0, stream>>>(feature, W1, S1t, N);
    k_adj_cvt <<<N / 64, 256, 0, stream>>>(adj, S1t, b1, h, a16, N, N);
    k_xw_t<NH2><<<N / 64, 256, 0, stream>>>(h, W2, S2t, N);
    k_adj_pre <<<N / 64, 256, 0, stream>>>(a16, S2t, b2, (float*)d_out, N, N);
    (void)in_sizes; (void)n_in; (void)out_size; (void)ws_size;
}

// Round 15
// 486.789 us; speedup vs baseline: 1.2480x; 1.2480x over previous
//
#include <hip/hip_runtime.h>
#include <stdint.h>

typedef float  f32x4  __attribute__((ext_vector_type(4)));
typedef short  short8 __attribute__((ext_vector_type(8)));
typedef __bf16 bf16x8 __attribute__((ext_vector_type(8)));

__device__ __forceinline__ unsigned short f2bf(float f) {
    unsigned u = __builtin_bit_cast(unsigned, f);
    unsigned r = u + 0x7fffu + ((u >> 16) & 1u);   // round-to-nearest-even
    return (unsigned short)(r >> 16);
}

__device__ __forceinline__ short8 cvt8(f32x4 a, f32x4 b) {
    short8 r;
    r[0] = (short)f2bf(a[0]); r[1] = (short)f2bf(a[1]);
    r[2] = (short)f2bf(a[2]); r[3] = (short)f2bf(a[3]);
    r[4] = (short)f2bf(b[0]); r[5] = (short)f2bf(b[1]);
    r[6] = (short)f2bf(b[2]); r[7] = (short)f2bf(b[3]);
    return r;
}

typedef const __attribute__((address_space(1))) void* gas_p;
typedef __attribute__((address_space(3))) void*       las_p;
__device__ __forceinline__ void gld_lds16(const void* g, void* l) {
    __builtin_amdgcn_global_load_lds((gas_p)g, (las_p)l, 16, 0, 0);
}

__device__ __forceinline__ f32x4 mfma16(short8 a, short8 b, f32x4 c) {
    return __builtin_amdgcn_mfma_f32_16x16x32_bf16(
        __builtin_bit_cast(bf16x8, a), __builtin_bit_cast(bf16x8, b), c, 0, 0, 0);
}

// ---------------------------------------------------------------------------
// Small GEMM:  St[n][m] = sum_k X[m][k] * W[k][n]   (K = 128 fixed)
// (validated, ~2% of runtime)
// ---------------------------------------------------------------------------
template<int NMAT>
__global__ __launch_bounds__(256) void k_xw_t(const float* __restrict__ X,
                                              const float* __restrict__ W,
                                              short* __restrict__ St, int M) {
    constexpr int K   = 128;
    constexpr int NPT = NMAT / 4;
    __shared__ float Xs[64][129];
    __shared__ float Ws[K][NMAT];

    const int tid = threadIdx.x;
    const int m0  = blockIdx.x * 64;

    constexpr int WCH = K * NMAT / 4 / 256;
    #pragma unroll
    for (int j = 0; j < WCH; ++j) {
        int ch = tid + j * 256;
        ((float4*)Ws)[ch] = ((const float4*)W)[ch];
    }
    #pragma unroll
    for (int j = 0; j < 8; ++j) {
        int ch = tid + j * 256;
        int r = ch >> 5, c4 = ch & 31;
        float4 v = *(const float4*)(X + (size_t)(m0 + r) * K + c4 * 4);
        Xs[r][c4 * 4 + 0] = v.x; Xs[r][c4 * 4 + 1] = v.y;
        Xs[r][c4 * 4 + 2] = v.z; Xs[r][c4 * 4 + 3] = v.w;
    }
    __syncthreads();

    const int m  = tid & 63;
    const int n0 = (tid >> 6) * NPT;
    float acc[NPT];
    #pragma unroll
    for (int i = 0; i < NPT; ++i) acc[i] = 0.f;

    for (int k = 0; k < K; ++k) {
        float x = Xs[m][k];
        #pragma unroll
        for (int i = 0; i < NPT; i += 4) {
            float4 w = *(const float4*)&Ws[k][n0 + i];
            acc[i + 0] += x * w.x; acc[i + 1] += x * w.y;
            acc[i + 2] += x * w.z; acc[i + 3] += x * w.w;
        }
    }
    #pragma unroll
    for (int i = 0; i < NPT; ++i)
        St[(size_t)(n0 + i) * M + m0 + m] = (short)f2bf(acc[i]);
}

// ---------------------------------------------------------------------------
// Streaming GEMM:  out[m][n] = sum_k adj[m][k] * S[k][n]  (+bias, opt. relu)
//  v15 = EXACT v11 revert (best measured: 487 us, passed).
//  r14's k-rotation failed correctness for reasons not yet understood;
//  no reorder variants until explained. This access pattern's empirical
//  ceiling on this chip is ~4.7 TB/s (6 structural families bracket it);
//  at 2.15 GiB mandatory adj traffic that puts this kernel within a few
//  percent of the pattern roofline.
//  - BM=64, 4 waves x 16 exclusive rows, batch-4 A prefetch (1 KB/row burst),
//    two 16-slot reg batches (all indices literal), (256,1) -> no spill.
//  - B: global_load_lds DMA, quad-buffered, ONE barrier/iter.
//  - Phase-counted vmcnt: VMH=BCH+16 at phases {0,3}, VML=BCH at {1,2};
//    forces {A(t),B(t)} retired, keeps newest stage in flight across barriers.
//  - XOR swizzle (row&7)<<4 on B (pre-swizzled DMA source, linear dest).
// ---------------------------------------------------------------------------
template<int BN, bool RELU>
__global__ __launch_bounds__(256, 1) void k_adj_gemm(const float* __restrict__ A,
                                                     const short* __restrict__ Bt,
                                                     const float* __restrict__ bias,
                                                     float* __restrict__ out,
                                                     int M, int K) {
    constexpr int BM   = 64, BK = 64;
    constexpr int NF   = BN / 16;                    // n-frags (full width): 8 or 4
    constexpr int BCH  = BN * BK * 2 / (256 * 16);   // B-DMA per thread per tile: 4 or 2
    constexpr int VMH  = BCH + 16;                   // phases 0,3
    constexpr int VML  = BCH;                        // phases 1,2

    __shared__ short Bs[4][BN * 64];                 // 4 x 16/8 KB

    const int tid  = threadIdx.x;
    const int wave = tid >> 6, lane = tid & 63;
    const int lr   = lane & 15, lk = lane >> 4;
    const int row0 = blockIdx.x * BM;
    const int row_g = row0 + wave * 16 + lr;         // wave-exclusive rows

    const char* Abase = (const char*)A + (size_t)row_g * K * 4 + lk * 32;

    const int key   = (lr & 7) << 4;                 // XOR swizzle key
    const int offs0 = (lk * 16) ^ key;               // B k-half 0
    const int offs1 = (64 + lk * 16) ^ key;          // B k-half 1

    f32x4 acc[NF];
    #pragma unroll
    for (int n = 0; n < NF; ++n) acc[n] = (f32x4)0.f;

    f32x4 bA0[16], bA1[16];                          // two 4-tile A batches
    const int NT  = K / BK;                          // 256
    const int NTM = NT - 1;

#define LOAD_SLOT(QARR, BI, TT)                                                 \
    {                                                                           \
        const char* p = Abase + (size_t)(TT) * 256;                             \
        QARR[(BI) + 0] = *(const f32x4*)(p);                                    \
        QARR[(BI) + 1] = *(const f32x4*)(p + 16);                               \
        QARR[(BI) + 2] = *(const f32x4*)(p + 128);                              \
        QARR[(BI) + 3] = *(const f32x4*)(p + 144);                              \
    }
#define LOAD_BATCH(QARR, T0)                                                    \
    {                                                                           \
        LOAD_SLOT(QARR, 0,  ((T0) + 0) & NTM)                                   \
        LOAD_SLOT(QARR, 4,  ((T0) + 1) & NTM)                                   \
        LOAD_SLOT(QARR, 8,  ((T0) + 2) & NTM)                                   \
        LOAD_SLOT(QARR, 12, ((T0) + 3) & NTM)                                   \
    }
#define STAGE_B(BUF, KTP)                                                       \
    {                                                                           \
        _Pragma("unroll")                                                       \
        for (int j = 0; j < BCH; ++j) {                                         \
            int o = (tid + j * 256) * 16;        /* linear byte off, B tile */  \
            int r = o >> 7, w = o & 127;                                        \
            const char* src = (const char*)Bt + (size_t)r * (K * 2)             \
                              + (size_t)((KTP) & NTM) * 128 + (w ^ ((r & 7) << 4)); \
            gld_lds16(src, (char*)&Bs[BUF][0] + o);                             \
        }                                                                       \
    }

    // prologue: batch0 (tiles 0-3), B(0), batch1 (tiles 4-7).
    // -> ops newer than B(0) at iter 0: batch1(16) + B(1)(BCH) = VMH. Exact.
    LOAD_BATCH(bA0, 0)
    STAGE_B(0, 0)
    LOAD_BATCH(bA1, 4)

#define ITER(KT, QARR, J4, CB, NB, VM, BATCH_STMT)                              \
    {                                                                           \
        /* cvt A(t) (compiler waits exactly on these 4 slots) */                \
        short8 fa0 = cvt8(QARR[(J4) + 0], QARR[(J4) + 1]);                      \
        short8 fa1 = cvt8(QARR[(J4) + 2], QARR[(J4) + 3]);                      \
        { int ktn = ((KT) + 1) & NTM; STAGE_B(NB, ktn) }                        \
        BATCH_STMT                                                              \
        __builtin_amdgcn_sched_barrier(0);                                      \
        /* force {A(t),B(t)} retired; newest batch/B-stage stay in flight */    \
        asm volatile("s_waitcnt vmcnt(%0)" :: "i"(VM) : "memory");              \
        __builtin_amdgcn_s_barrier();            /* the ONLY barrier */         \
        __builtin_amdgcn_sched_barrier(0);                                      \
        _Pragma("unroll")                                                       \
        for (int n = 0; n < NF; ++n) {                                          \
            short8 b0 = *(const short8*)((const char*)&Bs[CB][0]                \
                                         + n * 2048 + lr * 128 + offs0);        \
            acc[n] = mfma16(fa0, b0, acc[n]);                                   \
            short8 b1 = *(const short8*)((const char*)&Bs[CB][0]                \
                                         + n * 2048 + lr * 128 + offs1);        \
            acc[n] = mfma16(fa1, b1, acc[n]);                                   \
        }                                                                       \
    }

    // period-8 schedule: A batch q=(t>>2)&1 phase t&3; B buf t&3. 256 = 32*8.
    for (int g = 0; g < 32; ++g) {
        int t = g * 8;
        ITER(t + 0, bA0, 0,  0, 1, VMH, )
        ITER(t + 1, bA0, 4,  1, 2, VML, )
        ITER(t + 2, bA0, 8,  2, 3, VML, )
        ITER(t + 3, bA0, 12, 3, 0, VMH, LOAD_BATCH(bA0, (t + 3) + 5))
        ITER(t + 4, bA1, 0,  0, 1, VMH, )
        ITER(t + 5, bA1, 4,  1, 2, VML, )
        ITER(t + 6, bA1, 8,  2, 3, VML, )
        ITER(t + 7, bA1, 12, 3, 0, VMH, LOAD_BATCH(bA1, (t + 7) + 5))
    }
#undef ITER
#undef STAGE_B
#undef LOAD_BATCH
#undef LOAD_SLOT

    // epilogue: D layout col = lane&15, row = (lane>>4)*4 + j  [m89-verified]
    #pragma unroll
    for (int n = 0; n < NF; ++n) {
        int col = n * 16 + lr;
        float bv = bias[col];
        #pragma unroll
        for (int j = 0; j < 4; ++j) {
            int row = row0 + wave * 16 + lk * 4 + j;
            float v = acc[n][j] + bv;
            if (RELU) v = fmaxf(v, 0.f);
            out[(size_t)row * BN + col] = v;
        }
    }
}

extern "C" void kernel_launch(void* const* d_in, const int* in_sizes, int n_in,
                              void* d_out, int out_size, void* d_ws, size_t ws_size,
                              hipStream_t stream) {
    const int N = 16384, NH1 = 128, NH2 = 64;
    const float* feature = (const float*)d_in[0];
    const float* adj     = (const float*)d_in[1];
    const float* W1      = (const float*)d_in[2];
    const float* b1      = (const float*)d_in[3];
    const float* W2      = (const float*)d_in[4];
    const float* b2      = (const float*)d_in[5];

    short* S1t = (short*)d_ws;                            // [128][16384] bf16, 4 MiB
    float* h   = (float*)((char*)d_ws + (4u << 20));      // [16384][128] fp32, 8 MiB
    short* S2t = (short*)((char*)d_ws + (12u << 20));     // [64][16384]  bf16, 2 MiB

    k_xw_t<NH1><<<N / 64, 256, 0, stream>>>(feature, W1, S1t, N);
    k_adj_gemm<NH1, true ><<<N / 64, 256, 0, stream>>>(adj, S1t, b1, h, N, N);
    k_xw_t<NH2><<<N / 64, 256, 0, stream>>>(h, W2, S2t, N);
    k_adj_gemm<NH2, false><<<N / 64, 256, 0, stream>>>(adj, S2t, b2, (float*)d_out, N, N);
    (void)in_sizes; (void)n_in; (void)out_size; (void)ws_size;
}